// Round 9
// baseline (84.465 us; speedup 1.0000x reference)
//
#include <hip/hip_runtime.h>

// BitConv2d: x (16,32,224,224) f32, w (32,32,3,3) f32, out (16,32,224,224) f32.
// out = conv(x_q, w_q) * (x_scale/127 * w_scale); x_q in [-128,127], w_q in {-1,0,1}.
// Both exact in bf16 -> bf16 MFMA computes the integer conv exactly (|sum| < 2^24).
//
// 2 dispatches: absmax (2049 blocks: 2048 XCD-affine x-slices + 1 weight block),
// conv (1568 blocks x one 16x32 tile; prologue reduces the 2048 slot maxima).
// XCD-affinity: conv XCD k (blockIdx%8 round-robin) handles images 2k,2k+1;
// absmax block b warms XCD (b&7)'s L2 with those same images, descending address
// order so the L2 ends holding the image head (low h) where conv starts.

typedef __attribute__((ext_vector_type(8))) short short8;
typedef __attribute__((ext_vector_type(4))) float f32x4;

#define HW    224
#define NCH   32
#define PLANE (HW * HW)   // 50176
#define TH 16
#define TW 32
#define PAIR_F4 802816    // 2 images in float4s: 2*32*224*224/4
#define SLICE_F4 3136     // PAIR_F4 / 256 blocks per pair

__device__ __forceinline__ int lds_h(int pix, int c) {
    int sw = (pix & 3) ^ ((pix >> 2) & 3);
    return pix * 32 + (c & 7) + ((((c >> 3) ^ sw) & 3) << 3);
}

__device__ __forceinline__ unsigned short q8(float v) {
    float q = rintf(fminf(127.f, fmaxf(-128.f, v)));   // round-half-even like jnp.round
    return (unsigned short)(__float_as_uint(q) >> 16); // exact bf16 of small ints
}

// ws layout: [0, 8192) = u32 slots[2048] (fully rewritten each call);
// 8192: scal[0] = wscale; 8448: wbuf 18 frags x 512 bf16.
// frag (tap*2+kb): lane l elem j = w_q[kout = kb*16+(l&15)][c = (l>>4)*8+j][tap/3][tap%3]

__global__ __launch_bounds__(256) void absmax_kernel(const float* __restrict__ x,
                                                     const float* __restrict__ w,
                                                     unsigned* __restrict__ slots,
                                                     float* __restrict__ scal,
                                                     unsigned short* __restrict__ wbuf)
{
    int tid = threadIdx.x;
    int lane = tid & 63, wv = tid >> 6;

    if (blockIdx.x == 2048) {
        // ---- weight block: wscale = mean|w|, quantize into MFMA B-frag layout ----
        float s = 0.f;
        for (int i = tid; i < 9216; i += 256) s += fabsf(w[i]);
        #pragma unroll
        for (int off = 32; off > 0; off >>= 1) s += __shfl_xor(s, off);
        __shared__ float sm[4];
        __shared__ float s_ws;
        if (lane == 0) sm[wv] = s;
        __syncthreads();
        if (tid == 0) {
            float wscale = (sm[0] + sm[1] + sm[2] + sm[3]) / 9216.f + 1e-5f;
            scal[0] = wscale;
            s_ws = wscale;
        }
        __syncthreads();
        float wscale = s_ws;
        for (int o = tid; o < 9216; o += 256) {
            int frag = o >> 9, rem = o & 511;
            int l = rem >> 3, j = rem & 7;
            int tap = frag >> 1, kb = frag & 1;
            int kout = kb * 16 + (l & 15);
            int c = ((l >> 4) << 3) + j;
            int r = tap / 3, ss = tap % 3;
            float wv2 = w[((kout * 32 + c) * 3 + r) * 3 + ss];
            float q = fminf(1.f, fmaxf(-1.f, rintf(wv2 / wscale)));
            wbuf[o] = (unsigned short)(__float_as_uint(q) >> 16);   // exact bf16
        }
        return;
    }

    // ---- XCD-affine x-slice absmax ----
    // pair p = blockIdx&7 (same XCD as conv's chunk k=p under round-robin dispatch);
    // sub-slice q descending in address so L2 ends warm at the image-pair head.
    int p = blockIdx.x & 7;
    int q = blockIdx.x >> 3;                 // 0..255
    const float4* x4 = (const float4*)x + (long)p * PAIR_F4 + (255 - q) * SLICE_F4;
    float m = 0.f;
    for (int i = tid; i < SLICE_F4; i += 256) {
        float4 v = x4[i];
        m = fmaxf(m, fmaxf(fmaxf(fabsf(v.x), fabsf(v.y)),
                           fmaxf(fabsf(v.z), fabsf(v.w))));
    }
    #pragma unroll
    for (int off = 32; off > 0; off >>= 1)
        m = fmaxf(m, __shfl_xor(m, off));
    __shared__ float wm[4];
    if (lane == 0) wm[wv] = m;
    __syncthreads();
    if (tid == 0) {
        m = fmaxf(fmaxf(wm[0], wm[1]), fmaxf(wm[2], wm[3]));
        slots[blockIdx.x] = __float_as_uint(m);   // plain store, no atomics
    }
}

__global__ __launch_bounds__(512, 2) void conv_kernel(const float* __restrict__ x,
                                                      const unsigned short* __restrict__ wbuf,
                                                      const unsigned* __restrict__ slots,
                                                      const float* __restrict__ scal,
                                                      float* __restrict__ out)
{
    __shared__ __align__(16) unsigned short xs[612 * 32];
    __shared__ float sred[8];

    // bijective XCD swizzle: 1568 blocks = 8 XCDs x 196 contiguous (= 2 images each)
    int bid = (blockIdx.x & 7) * 196 + (blockIdx.x >> 3);
    int tw = bid % 7;
    int rest = bid / 7;
    int th = rest % 14;
    int n  = rest / 14;
    int h0 = th * TH, w0 = tw * TW;

    int tid = threadIdx.x;
    int lane = tid & 63, wv = tid >> 6;

    const float* xn = x + n * (NCH * PLANE);

    // staging map: slot = tid&7 (4-px col group), c = (tid>>3)&31, half = tid>>8
    int slot = tid & 7;
    int c = (tid >> 3) & 31;
    int hbase = (tid >> 8) * 9;
    const float* tb = xn + c * PLANE + w0 + slot * 4;
    int pixb = 1 + slot * 4;

    // ---- issue order: slots first (reduce waits only on this), then all x loads ----
    uint4 sv = ((const uint4*)slots)[tid];
    float wscale = scal[0];

    float hv[3];
    #pragma unroll
    for (int it = 0; it < 3; ++it) {
        int e = tid + it * 512;
        hv[it] = 0.f;
        if (e < 1152) {
            int side = e & 1, cc = (e >> 1) & 31, hp = e >> 6;
            int gh = h0 - 1 + hp;
            int gw = side ? (w0 + TW) : (w0 - 1);
            int ghc = gh < 0 ? 0 : (gh > HW - 1 ? HW - 1 : gh);
            int gwc = gw < 0 ? 0 : (gw > HW - 1 ? HW - 1 : gw);
            hv[it] = xn[cc * PLANE + ghc * HW + gwc];
        }
    }
    float4 va[5], vb[4];
    #pragma unroll
    for (int i = 0; i < 5; ++i) {
        int gh = h0 - 1 + hbase + i;
        int ghc = gh < 0 ? 0 : (gh > HW - 1 ? HW - 1 : gh);
        va[i] = *(const float4*)(tb + ghc * HW);
    }
    #pragma unroll
    for (int i = 0; i < 4; ++i) {
        int gh = h0 + 4 + hbase + i;      // rows hbase+5..hbase+8
        int ghc = gh < 0 ? 0 : (gh > HW - 1 ? HW - 1 : gh);
        vb[i] = *(const float4*)(tb + ghc * HW);
    }

    // ---- xmax reduce (x loads still in flight) ----
    float m2 = fmaxf(fmaxf(__uint_as_float(sv.x), __uint_as_float(sv.y)),
                     fmaxf(__uint_as_float(sv.z), __uint_as_float(sv.w)));
    #pragma unroll
    for (int off = 32; off > 0; off >>= 1)
        m2 = fmaxf(m2, __shfl_xor(m2, off));
    if (lane == 0) sred[wv] = m2;
    __syncthreads();
    float xmax = fmaxf(fmaxf(fmaxf(sred[0], sred[1]), fmaxf(sred[2], sred[3])),
                       fmaxf(fmaxf(sred[4], sred[5]), fmaxf(sred[6], sred[7])));
    float xscale = xmax + 1e-5f;
    float inv = 127.f / xscale;
    float osc = (xscale / 127.f) * wscale;

    // ---- quantize + LDS writes, batch A then halo then batch B (progressive drain) ----
    #pragma unroll
    for (int i = 0; i < 5; ++i) {
        int gh = h0 - 1 + hbase + i;
        float vs = ((unsigned)gh < (unsigned)HW) ? inv : 0.f;
        int p0 = (hbase + i) * 34 + pixb;
        xs[lds_h(p0 + 0, c)] = q8(va[i].x * vs);
        xs[lds_h(p0 + 1, c)] = q8(va[i].y * vs);
        xs[lds_h(p0 + 2, c)] = q8(va[i].z * vs);
        xs[lds_h(p0 + 3, c)] = q8(va[i].w * vs);
    }
    #pragma unroll
    for (int it = 0; it < 3; ++it) {
        int e = tid + it * 512;
        if (e < 1152) {
            int side = e & 1, cc = (e >> 1) & 31, hp = e >> 6;
            int gh = h0 - 1 + hp;
            int gw = side ? (w0 + TW) : (w0 - 1);
            float vs = ((unsigned)gh < (unsigned)HW && (unsigned)gw < (unsigned)HW)
                           ? inv : 0.f;
            xs[lds_h(hp * 34 + (side ? 33 : 0), cc)] = q8(hv[it] * vs);
        }
    }
    #pragma unroll
    for (int i = 0; i < 4; ++i) {
        int gh = h0 + 4 + hbase + i;
        float vs = ((unsigned)gh < (unsigned)HW) ? inv : 0.f;
        int p0 = (hbase + 5 + i) * 34 + pixb;
        xs[lds_h(p0 + 0, c)] = q8(vb[i].x * vs);
        xs[lds_h(p0 + 1, c)] = q8(vb[i].y * vs);
        xs[lds_h(p0 + 2, c)] = q8(vb[i].z * vs);
        xs[lds_h(p0 + 3, c)] = q8(vb[i].w * vs);
    }
    __syncthreads();

    // ---- MFMA: 9 taps x [2 row][2 pixblock][2 kblock], one-ahead weight prefetch ----
    int ln = lane & 15, cb = lane >> 4;
    f32x4 acc[2][2][2] = {};
    const short8* wfp = (const short8*)wbuf;
    short8 wa = wfp[lane];
    short8 wb = wfp[64 + lane];
    for (int tap = 0; tap < 9; ++tap) {
        short8 na, nb;
        if (tap < 8) {
            na = wfp[(2 * tap + 2) * 64 + lane];
            nb = wfp[(2 * tap + 3) * 64 + lane];
        }
        int r = tap / 3;
        int s2 = tap - r * 3;
        #pragma unroll
        for (int ri = 0; ri < 2; ++ri) {
            #pragma unroll
            for (int pb = 0; pb < 2; ++pb) {
                int pix = (wv * 2 + ri + r) * 34 + pb * 16 + ln + s2;
                int sw = (pix & 3) ^ ((pix >> 2) & 3);
                const short8 a = *(const short8*)&xs[pix * 32 + (((cb ^ sw) & 3) << 3)];
                acc[ri][pb][0] = __builtin_amdgcn_mfma_f32_16x16x32_bf16(
                    a, wa, acc[ri][pb][0], 0, 0, 0);
                acc[ri][pb][1] = __builtin_amdgcn_mfma_f32_16x16x32_bf16(
                    a, wb, acc[ri][pb][1], 0, 0, 0);
            }
        }
        wa = na;
        wb = nb;
    }

    // ---- epilogue: D row = pixel -> lane holds 4 consecutive px: float4 stores ----
    float* on = out + n * (NCH * PLANE);
    #pragma unroll
    for (int ri = 0; ri < 2; ++ri) {
        int h = h0 + wv * 2 + ri;
        #pragma unroll
        for (int pb = 0; pb < 2; ++pb) {
            int wcol = w0 + pb * 16 + cb * 4;
            #pragma unroll
            for (int kb = 0; kb < 2; ++kb) {
                int k = kb * 16 + ln;
                f32x4 o;
                o[0] = acc[ri][pb][kb][0] * osc;
                o[1] = acc[ri][pb][kb][1] * osc;
                o[2] = acc[ri][pb][kb][2] * osc;
                o[3] = acc[ri][pb][kb][3] * osc;
                *(f32x4*)&on[(k * HW + h) * HW + wcol] = o;
            }
        }
    }
}

extern "C" void kernel_launch(void* const* d_in, const int* in_sizes, int n_in,
                              void* d_out, int out_size, void* d_ws, size_t ws_size,
                              hipStream_t stream)
{
    const float* x = (const float*)d_in[0];
    const float* w = (const float*)d_in[1];
    float* outp = (float*)d_out;
    unsigned* slots = (unsigned*)d_ws;
    float* scal = (float*)((char*)d_ws + 8192);
    unsigned short* wbuf = (unsigned short*)((char*)d_ws + 8448);

    absmax_kernel<<<2049, 256, 0, stream>>>(x, w, slots, scal, wbuf);
    conv_kernel<<<16 * 14 * 7, 512, 0, stream>>>(x, wbuf, slots, scal, outp);
}

// Round 10
// 83.885 us; speedup vs baseline: 1.0069x; 1.0069x over previous
//
#include <hip/hip_runtime.h>
#include <hip/hip_cooperative_groups.h>

namespace cg = cooperative_groups;

// BitConv2d: x (16,32,224,224) f32, w (32,32,3,3) f32, out (16,32,224,224) f32.
// out = conv(x_q, w_q) * (x_scale/127 * w_scale); x_q in [-128,127], w_q in {-1,0,1}.
// Both exact in bf16 -> bf16 MFMA computes the integer conv exactly (|sum| < 2^24).
//
// Primary: ONE cooperative kernel, 512 blocks x 512 thr (2/CU guaranteed-resident):
//   A: per-block x-slice absmax + redundant wscale + distributed weight quant
//   grid.sync()
//   B: 512-slot xmax reduce per block
//   C: conv tiles (8x32) pulled from 8 per-XCD work-steal queues (392 tiles each)
// Fallback (residency/launch failure): round-8 two-dispatch path, known-good.

typedef __attribute__((ext_vector_type(8))) short short8;
typedef __attribute__((ext_vector_type(4))) float f32x4;

#define HW    224
#define NCH   32
#define PLANE (HW * HW)          // 50176
#define TW    32
#define NX4   (16 * NCH * PLANE / 4)   // 6422528
#define PAIR_F4 802816           // 2 images in float4s
#define SLICE 12544              // NX4 / 512

__device__ __forceinline__ int lds_h(int pix, int c) {
    int sw = (pix & 3) ^ ((pix >> 2) & 3);
    return pix * 32 + (c & 7) + ((((c >> 3) ^ sw) & 3) << 3);
}

__device__ __forceinline__ unsigned short q8(float v) {
    float q = rintf(fminf(127.f, fmaxf(-128.f, v)));   // round-half-even like jnp.round
    return (unsigned short)(__float_as_uint(q) >> 16); // exact bf16 of small ints
}

// ===================== fused cooperative kernel =====================
// ws (fused): [0,2048) u32 slots[512]; 2048: u32 cnt[8]; 2176: wbuf 18x512 bf16.
__global__ __launch_bounds__(512, 2) void fused_kernel(const float* __restrict__ x,
                                                       const float* __restrict__ w,
                                                       float* __restrict__ out,
                                                       unsigned char* __restrict__ wsb)
{
    unsigned* slots = (unsigned*)wsb;
    unsigned* cnt = (unsigned*)(wsb + 2048);
    unsigned short* wbuf = (unsigned short*)(wsb + 2176);

    __shared__ __align__(16) unsigned short xs[340 * 32];   // 10 rows x 34 cols x 32ch
    __shared__ float sredA[8], sredB[8];
    __shared__ int s_tile;

    int tid = threadIdx.x, lane = tid & 63, wv = tid >> 6;
    int bx = blockIdx.x;

    if (tid == 0 && bx < 8) cnt[bx] = 0u;   // steal counters, re-init every call

    // ---- phase A: wscale partial (identical in every block) + x-slice absmax ----
    float s = 0.f;
    #pragma unroll
    for (int k = 0; k < 18; ++k) s += fabsf(w[tid + 512 * k]);   // 512*18 = 9216

    const float4* xsl = (const float4*)x + (long)(bx & 7) * PAIR_F4 + (bx >> 3) * SLICE;
    float m = 0.f;
    for (int i = tid; i < SLICE; i += 512) {
        float4 v = xsl[i];
        m = fmaxf(m, fmaxf(fmaxf(fabsf(v.x), fabsf(v.y)),
                           fmaxf(fabsf(v.z), fabsf(v.w))));
    }
    #pragma unroll
    for (int off = 32; off; off >>= 1) {
        s += __shfl_xor(s, off);
        m = fmaxf(m, __shfl_xor(m, off));
    }
    if (lane == 0) { sredA[wv] = m; sredB[wv] = s; }
    __syncthreads();
    float bm = fmaxf(fmaxf(fmaxf(sredA[0], sredA[1]), fmaxf(sredA[2], sredA[3])),
                     fmaxf(fmaxf(sredA[4], sredA[5]), fmaxf(sredA[6], sredA[7])));
    float wsum = ((sredB[0] + sredB[1]) + (sredB[2] + sredB[3])) +
                 ((sredB[4] + sredB[5]) + (sredB[6] + sredB[7]));
    float wscale = wsum / 9216.f + 1e-5f;      // identical across blocks (same op order)
    if (tid == 0) slots[bx] = __float_as_uint(bm);
    if (tid < 18) {   // distributed weight quant: block bx covers o in [bx*18, bx*18+18)
        int o = bx * 18 + tid;
        int frag = o >> 9, rem = o & 511;
        int l = rem >> 3, j = rem & 7;
        int tap = frag >> 1, kb = frag & 1;
        int kout = kb * 16 + (l & 15);
        int c = ((l >> 4) << 3) + j;
        int r = tap / 3, ss = tap % 3;
        float wv2 = w[((kout * 32 + c) * 3 + r) * 3 + ss];
        float q = fminf(1.f, fmaxf(-1.f, rintf(wv2 / wscale)));
        wbuf[o] = (unsigned short)(__float_as_uint(q) >> 16);   // exact bf16 of {-1,0,1}
    }

    cg::this_grid().sync();

    // ---- phase B: xmax from 512 slots ----
    float m2 = __uint_as_float(slots[tid & 511]);
    #pragma unroll
    for (int off = 32; off; off >>= 1) m2 = fmaxf(m2, __shfl_xor(m2, off));
    if (lane == 0) sredA[wv] = m2;
    __syncthreads();
    float xmax = fmaxf(fmaxf(fmaxf(sredA[0], sredA[1]), fmaxf(sredA[2], sredA[3])),
                       fmaxf(fmaxf(sredA[4], sredA[5]), fmaxf(sredA[6], sredA[7])));
    float xscale = xmax + 1e-5f;
    float inv = 127.f / xscale;
    float osc = (xscale / 127.f) * wscale;

    // ---- phase C: work-steal conv tiles, 8x32 each, per-XCD queues ----
    int xcd = bx & 7;                       // matches round-robin block->XCD
    const short8* wfp = (const short8*)wbuf;
    int slot = tid & 7;
    int c2 = (tid >> 3) & 31;
    int half = (tid >> 8) & 1;
    int pixb = 1 + slot * 4;
    int ln = lane & 15, cb = lane >> 4;

    for (;;) {
        __syncthreads();                    // protect xs + s_tile
        if (tid == 0) s_tile = (int)atomicAdd(&cnt[xcd], 1u);
        __syncthreads();
        int t = s_tile;
        if (t >= 392) break;                // 2 images x 28 th x 7 tw
        int n = 2 * xcd + (t >= 196);
        int tt = (t >= 196) ? t - 196 : t;
        int th = tt / 7, tw = tt - th * 7;
        int h0 = th * 8, w0 = tw * TW;
        const float* xn = x + n * (NCH * PLANE);
        const float* tb = xn + c2 * PLANE + w0 + slot * 4;

        // issue all tile loads (clamped addresses, OOB masked at quantize)
        float4 va[5];
        float hv[2];
        #pragma unroll
        for (int i = 0; i < 5; ++i) {
            int gh = h0 - 1 + half * 5 + i;
            int ghc = gh < 0 ? 0 : (gh > HW - 1 ? HW - 1 : gh);
            va[i] = *(const float4*)(tb + ghc * HW);
        }
        #pragma unroll
        for (int rep = 0; rep < 2; ++rep) {  // halo cols: 10 rows x 32ch x 2 = 640
            int e = tid + rep * 512;
            hv[rep] = 0.f;
            if (e < 640) {
                int side = e & 1, cc = (e >> 1) & 31, hp = e >> 6;
                int gh = h0 - 1 + hp;
                int gw = side ? (w0 + TW) : (w0 - 1);
                int ghc = gh < 0 ? 0 : (gh > HW - 1 ? HW - 1 : gh);
                int gwc = gw < 0 ? 0 : (gw > HW - 1 ? HW - 1 : gw);
                hv[rep] = xn[cc * PLANE + ghc * HW + gwc];
            }
        }
        // quantize + LDS
        #pragma unroll
        for (int i = 0; i < 5; ++i) {
            int gh = h0 - 1 + half * 5 + i;
            float vs = ((unsigned)gh < (unsigned)HW) ? inv : 0.f;
            int p0 = (half * 5 + i) * 34 + pixb;
            xs[lds_h(p0 + 0, c2)] = q8(va[i].x * vs);
            xs[lds_h(p0 + 1, c2)] = q8(va[i].y * vs);
            xs[lds_h(p0 + 2, c2)] = q8(va[i].z * vs);
            xs[lds_h(p0 + 3, c2)] = q8(va[i].w * vs);
        }
        #pragma unroll
        for (int rep = 0; rep < 2; ++rep) {
            int e = tid + rep * 512;
            if (e < 640) {
                int side = e & 1, cc = (e >> 1) & 31, hp = e >> 6;
                int gh = h0 - 1 + hp;
                int gw = side ? (w0 + TW) : (w0 - 1);
                float vs = ((unsigned)gh < (unsigned)HW && (unsigned)gw < (unsigned)HW)
                               ? inv : 0.f;
                xs[lds_h(hp * 34 + (side ? 33 : 0), cc)] = q8(hv[rep] * vs);
            }
        }
        __syncthreads();

        // MFMA: wave wv owns output row h0+wv (32 px x 32 kout)
        f32x4 acc[2][2] = {};   // [pb][kb]
        short8 wa = wfp[lane];
        short8 wb = wfp[64 + lane];
        for (int tap = 0; tap < 9; ++tap) {
            short8 na, nb;
            if (tap < 8) {
                na = wfp[(2 * tap + 2) * 64 + lane];
                nb = wfp[(2 * tap + 3) * 64 + lane];
            }
            int r = tap / 3, s2 = tap - r * 3;
            #pragma unroll
            for (int pb = 0; pb < 2; ++pb) {
                int pix = (wv + r) * 34 + pb * 16 + ln + s2;
                int sw = (pix & 3) ^ ((pix >> 2) & 3);
                const short8 a = *(const short8*)&xs[pix * 32 + (((cb ^ sw) & 3) << 3)];
                acc[pb][0] = __builtin_amdgcn_mfma_f32_16x16x32_bf16(a, wa, acc[pb][0], 0, 0, 0);
                acc[pb][1] = __builtin_amdgcn_mfma_f32_16x16x32_bf16(a, wb, acc[pb][1], 0, 0, 0);
            }
            wa = na; wb = nb;
        }

        float* on = out + n * (NCH * PLANE);
        int h = h0 + wv;
        #pragma unroll
        for (int pb = 0; pb < 2; ++pb) {
            int wcol = w0 + pb * 16 + cb * 4;
            #pragma unroll
            for (int kb = 0; kb < 2; ++kb) {
                int k = kb * 16 + ln;
                f32x4 o;
                o[0] = acc[pb][kb][0] * osc;
                o[1] = acc[pb][kb][1] * osc;
                o[2] = acc[pb][kb][2] * osc;
                o[3] = acc[pb][kb][3] * osc;
                *(f32x4*)&on[(k * HW + h) * HW + wcol] = o;
            }
        }
    }
}

// ===================== fallback: round-8 two-dispatch path =====================
// ws (fallback): [0,8192) u32 slots[2048]; 8192: scal[0]=wscale; 8448: wbuf.
__global__ __launch_bounds__(256) void fb_absmax(const float* __restrict__ x,
                                                 const float* __restrict__ w,
                                                 unsigned* __restrict__ slots,
                                                 float* __restrict__ scal,
                                                 unsigned short* __restrict__ wbuf)
{
    int tid = threadIdx.x;
    int lane = tid & 63, wv = tid >> 6;

    if (blockIdx.x == 2048) {
        float s = 0.f;
        for (int i = tid; i < 9216; i += 256) s += fabsf(w[i]);
        #pragma unroll
        for (int off = 32; off > 0; off >>= 1) s += __shfl_xor(s, off);
        __shared__ float sm[4];
        __shared__ float s_ws;
        if (lane == 0) sm[wv] = s;
        __syncthreads();
        if (tid == 0) {
            float wscale = (sm[0] + sm[1] + sm[2] + sm[3]) / 9216.f + 1e-5f;
            scal[0] = wscale;
            s_ws = wscale;
        }
        __syncthreads();
        float wscale = s_ws;
        for (int o = tid; o < 9216; o += 256) {
            int frag = o >> 9, rem = o & 511;
            int l = rem >> 3, j = rem & 7;
            int tap = frag >> 1, kb = frag & 1;
            int kout = kb * 16 + (l & 15);
            int c = ((l >> 4) << 3) + j;
            int r = tap / 3, ss = tap % 3;
            float wv2 = w[((kout * 32 + c) * 3 + r) * 3 + ss];
            float q = fminf(1.f, fmaxf(-1.f, rintf(wv2 / wscale)));
            wbuf[o] = (unsigned short)(__float_as_uint(q) >> 16);
        }
        return;
    }
    const float4* x4 = (const float4*)x;
    float m = 0.f;
    for (int i = blockIdx.x * 256 + tid; i < NX4; i += 2048 * 256) {
        float4 v = x4[i];
        m = fmaxf(m, fmaxf(fmaxf(fabsf(v.x), fabsf(v.y)),
                           fmaxf(fabsf(v.z), fabsf(v.w))));
    }
    #pragma unroll
    for (int off = 32; off > 0; off >>= 1)
        m = fmaxf(m, __shfl_xor(m, off));
    __shared__ float wm[4];
    if (lane == 0) wm[wv] = m;
    __syncthreads();
    if (tid == 0) {
        m = fmaxf(fmaxf(wm[0], wm[1]), fmaxf(wm[2], wm[3]));
        slots[blockIdx.x] = __float_as_uint(m);
    }
}

__global__ __launch_bounds__(512, 2) void fb_conv(const float* __restrict__ x,
                                                  const unsigned short* __restrict__ wbuf,
                                                  const unsigned* __restrict__ slots,
                                                  const float* __restrict__ scal,
                                                  float* __restrict__ out)
{
    __shared__ __align__(16) unsigned short xs[612 * 32];
    __shared__ float sred[8];

    int bid = (blockIdx.x & 7) * 196 + (blockIdx.x >> 3);
    int tw = bid % 7;
    int rest = bid / 7;
    int th = rest % 14;
    int n  = rest / 14;
    int h0 = th * 16, w0 = tw * TW;

    int tid = threadIdx.x;
    int lane = tid & 63, wv = tid >> 6;
    const float* xn = x + n * (NCH * PLANE);

    int slot = tid & 7;
    int c = (tid >> 3) & 31;
    int hbase = (tid >> 8) * 9;
    const float* tb = xn + c * PLANE + w0 + slot * 4;
    int pixb = 1 + slot * 4;

    uint4 sv = ((const uint4*)slots)[tid];
    float wscale = scal[0];

    float hv[3];
    #pragma unroll
    for (int it = 0; it < 3; ++it) {
        int e = tid + it * 512;
        hv[it] = 0.f;
        if (e < 1152) {
            int side = e & 1, cc = (e >> 1) & 31, hp = e >> 6;
            int gh = h0 - 1 + hp;
            int gw = side ? (w0 + TW) : (w0 - 1);
            int ghc = gh < 0 ? 0 : (gh > HW - 1 ? HW - 1 : gh);
            int gwc = gw < 0 ? 0 : (gw > HW - 1 ? HW - 1 : gw);
            hv[it] = xn[cc * PLANE + ghc * HW + gwc];
        }
    }
    float4 va[5], vb[4];
    #pragma unroll
    for (int i = 0; i < 5; ++i) {
        int gh = h0 - 1 + hbase + i;
        int ghc = gh < 0 ? 0 : (gh > HW - 1 ? HW - 1 : gh);
        va[i] = *(const float4*)(tb + ghc * HW);
    }
    #pragma unroll
    for (int i = 0; i < 4; ++i) {
        int gh = h0 + 4 + hbase + i;
        int ghc = gh < 0 ? 0 : (gh > HW - 1 ? HW - 1 : gh);
        vb[i] = *(const float4*)(tb + ghc * HW);
    }

    float m2 = fmaxf(fmaxf(__uint_as_float(sv.x), __uint_as_float(sv.y)),
                     fmaxf(__uint_as_float(sv.z), __uint_as_float(sv.w)));
    #pragma unroll
    for (int off = 32; off > 0; off >>= 1)
        m2 = fmaxf(m2, __shfl_xor(m2, off));
    if (lane == 0) sred[wv] = m2;
    __syncthreads();
    float xmax = fmaxf(fmaxf(fmaxf(sred[0], sred[1]), fmaxf(sred[2], sred[3])),
                       fmaxf(fmaxf(sred[4], sred[5]), fmaxf(sred[6], sred[7])));
    float xscale = xmax + 1e-5f;
    float inv = 127.f / xscale;
    float osc = (xscale / 127.f) * wscale;

    #pragma unroll
    for (int i = 0; i < 5; ++i) {
        int gh = h0 - 1 + hbase + i;
        float vs = ((unsigned)gh < (unsigned)HW) ? inv : 0.f;
        int p0 = (hbase + i) * 34 + pixb;
        xs[lds_h(p0 + 0, c)] = q8(va[i].x * vs);
        xs[lds_h(p0 + 1, c)] = q8(va[i].y * vs);
        xs[lds_h(p0 + 2, c)] = q8(va[i].z * vs);
        xs[lds_h(p0 + 3, c)] = q8(va[i].w * vs);
    }
    #pragma unroll
    for (int it = 0; it < 3; ++it) {
        int e = tid + it * 512;
        if (e < 1152) {
            int side = e & 1, cc = (e >> 1) & 31, hp = e >> 6;
            int gh = h0 - 1 + hp;
            int gw = side ? (w0 + TW) : (w0 - 1);
            float vs = ((unsigned)gh < (unsigned)HW && (unsigned)gw < (unsigned)HW)
                           ? inv : 0.f;
            xs[lds_h(hp * 34 + (side ? 33 : 0), cc)] = q8(hv[it] * vs);
        }
    }
    #pragma unroll
    for (int i = 0; i < 4; ++i) {
        int gh = h0 + 4 + hbase + i;
        float vs = ((unsigned)gh < (unsigned)HW) ? inv : 0.f;
        int p0 = (hbase + 5 + i) * 34 + pixb;
        xs[lds_h(p0 + 0, c)] = q8(vb[i].x * vs);
        xs[lds_h(p0 + 1, c)] = q8(vb[i].y * vs);
        xs[lds_h(p0 + 2, c)] = q8(vb[i].z * vs);
        xs[lds_h(p0 + 3, c)] = q8(vb[i].w * vs);
    }
    __syncthreads();

    int ln = lane & 15, cb = lane >> 4;
    f32x4 acc[2][2][2] = {};
    const short8* wfp = (const short8*)wbuf;
    short8 wa = wfp[lane];
    short8 wb = wfp[64 + lane];
    for (int tap = 0; tap < 9; ++tap) {
        short8 na, nb;
        if (tap < 8) {
            na = wfp[(2 * tap + 2) * 64 + lane];
            nb = wfp[(2 * tap + 3) * 64 + lane];
        }
        int r = tap / 3;
        int s2 = tap - r * 3;
        #pragma unroll
        for (int ri = 0; ri < 2; ++ri) {
            #pragma unroll
            for (int pb = 0; pb < 2; ++pb) {
                int pix = (wv * 2 + ri + r) * 34 + pb * 16 + ln + s2;
                int sw = (pix & 3) ^ ((pix >> 2) & 3);
                const short8 a = *(const short8*)&xs[pix * 32 + (((cb ^ sw) & 3) << 3)];
                acc[ri][pb][0] = __builtin_amdgcn_mfma_f32_16x16x32_bf16(
                    a, wa, acc[ri][pb][0], 0, 0, 0);
                acc[ri][pb][1] = __builtin_amdgcn_mfma_f32_16x16x32_bf16(
                    a, wb, acc[ri][pb][1], 0, 0, 0);
            }
        }
        wa = na;
        wb = nb;
    }

    float* on = out + n * (NCH * PLANE);
    #pragma unroll
    for (int ri = 0; ri < 2; ++ri) {
        int h = h0 + wv * 2 + ri;
        #pragma unroll
        for (int pb = 0; pb < 2; ++pb) {
            int wcol = w0 + pb * 16 + cb * 4;
            #pragma unroll
            for (int kb = 0; kb < 2; ++kb) {
                int k = kb * 16 + ln;
                f32x4 o;
                o[0] = acc[ri][pb][kb][0] * osc;
                o[1] = acc[ri][pb][kb][1] * osc;
                o[2] = acc[ri][pb][kb][2] * osc;
                o[3] = acc[ri][pb][kb][3] * osc;
                *(f32x4*)&on[(k * HW + h) * HW + wcol] = o;
            }
        }
    }
}

extern "C" void kernel_launch(void* const* d_in, const int* in_sizes, int n_in,
                              void* d_out, int out_size, void* d_ws, size_t ws_size,
                              hipStream_t stream)
{
    const float* x = (const float*)d_in[0];
    const float* w = (const float*)d_in[1];
    float* outp = (float*)d_out;
    unsigned char* wsb = (unsigned char*)d_ws;

    // try the fused cooperative path only if 512 blocks are guaranteed co-resident
    int nb = 0;
    hipError_t qe = hipOccupancyMaxActiveBlocksPerMultiprocessor(
        &nb, (const void*)fused_kernel, 512, 0);
    if (qe == hipSuccess && nb >= 2) {
        void* args[] = { (void*)&x, (void*)&w, (void*)&outp, (void*)&wsb };
        hipError_t le = hipLaunchCooperativeKernel((const void*)fused_kernel,
                                                   dim3(512), dim3(512), args, 0, stream);
        if (le == hipSuccess) return;
    }
    (void)hipGetLastError();   // clear sticky error from the failed attempt

    // fallback: proven round-8 two-dispatch path
    unsigned* slots = (unsigned*)wsb;
    float* scal = (float*)(wsb + 8192);
    unsigned short* wbuf = (unsigned short*)(wsb + 8448);
    fb_absmax<<<2049, 256, 0, stream>>>(x, w, slots, scal, wbuf);
    fb_conv<<<16 * 14 * 7, 512, 0, stream>>>(x, wbuf, slots, scal, outp);
}

// Round 11
// 73.484 us; speedup vs baseline: 1.1494x; 1.1415x over previous
//
#include <hip/hip_runtime.h>

// BitConv2d: x (16,32,224,224) f32, w (32,32,3,3) f32, out (16,32,224,224) f32.
// out = conv(x_q, w_q) * (x_scale/127 * w_scale); x_q in [-128,127], w_q in {-1,0,1}.
// Both exact in bf16 -> bf16 MFMA computes the integer conv exactly (|sum| < 2^24).
//
// 2 dispatches: absmax (2049 blocks: 2048 x-slices + 1 weight-quant block),
// conv (3136 blocks x one 8x32 tile, 256 thr: 4-wave blocks -> 4 blocks/CU
// co-resident for cross-block phase overlap; VGPR capped 128 via (256,4)).

typedef __attribute__((ext_vector_type(8))) short short8;
typedef __attribute__((ext_vector_type(4))) float f32x4;

#define HW    224
#define NCH   32
#define PLANE (HW * HW)   // 50176
#define TH 8
#define TW 32
#define NX4   (16 * NCH * PLANE / 4)
// LDS tile: 340 pixels (10 rows x 34 cols) x 32 ch bf16 = 21760 B, granule-XOR swizzled.

__device__ __forceinline__ int lds_h(int pix, int c) {
    int sw = (pix & 3) ^ ((pix >> 2) & 3);
    return pix * 32 + (c & 7) + ((((c >> 3) ^ sw) & 3) << 3);
}

__device__ __forceinline__ unsigned short q8(float v) {
    float q = rintf(fminf(127.f, fmaxf(-128.f, v)));   // round-half-even like jnp.round
    return (unsigned short)(__float_as_uint(q) >> 16); // exact bf16 of small ints
}

// ws layout: [0, 8192) = u32 slots[2048] (fully rewritten each call);
// 8192: scal[0] = wscale; 8448: wbuf 18 frags x 512 bf16.
// frag (tap*2+kb): lane l elem j = w_q[kout = kb*16+(l&15)][c = (l>>4)*8+j][tap/3][tap%3]

__global__ __launch_bounds__(256) void absmax_kernel(const float* __restrict__ x,
                                                     const float* __restrict__ w,
                                                     unsigned* __restrict__ slots,
                                                     float* __restrict__ scal,
                                                     unsigned short* __restrict__ wbuf)
{
    int tid = threadIdx.x;
    int lane = tid & 63, wv = tid >> 6;

    if (blockIdx.x == 2048) {
        // ---- weight block: wscale = mean|w|, quantize into MFMA B-frag layout ----
        float s = 0.f;
        for (int i = tid; i < 9216; i += 256) s += fabsf(w[i]);
        #pragma unroll
        for (int off = 32; off > 0; off >>= 1) s += __shfl_xor(s, off);
        __shared__ float sm[4];
        __shared__ float s_ws;
        if (lane == 0) sm[wv] = s;
        __syncthreads();
        if (tid == 0) {
            float wscale = (sm[0] + sm[1] + sm[2] + sm[3]) / 9216.f + 1e-5f;
            scal[0] = wscale;
            s_ws = wscale;
        }
        __syncthreads();
        float wscale = s_ws;
        for (int o = tid; o < 9216; o += 256) {
            int frag = o >> 9, rem = o & 511;
            int l = rem >> 3, j = rem & 7;
            int tap = frag >> 1, kb = frag & 1;
            int kout = kb * 16 + (l & 15);
            int c = ((l >> 4) << 3) + j;
            int r = tap / 3, ss = tap % 3;
            float wv2 = w[((kout * 32 + c) * 3 + r) * 3 + ss];
            float q = fminf(1.f, fmaxf(-1.f, rintf(wv2 / wscale)));
            wbuf[o] = (unsigned short)(__float_as_uint(q) >> 16);   // exact bf16
        }
        return;
    }

    // ---- x-slice absmax ----
    const float4* x4 = (const float4*)x;
    float m = 0.f;
    for (int i = blockIdx.x * 256 + tid; i < NX4; i += 2048 * 256) {
        float4 v = x4[i];
        m = fmaxf(m, fmaxf(fmaxf(fabsf(v.x), fabsf(v.y)),
                           fmaxf(fabsf(v.z), fabsf(v.w))));
    }
    #pragma unroll
    for (int off = 32; off > 0; off >>= 1)
        m = fmaxf(m, __shfl_xor(m, off));
    __shared__ float wm[4];
    if (lane == 0) wm[wv] = m;
    __syncthreads();
    if (tid == 0) {
        m = fmaxf(fmaxf(wm[0], wm[1]), fmaxf(wm[2], wm[3]));
        slots[blockIdx.x] = __float_as_uint(m);   // plain store, no atomics
    }
}

__global__ __launch_bounds__(256, 4) void conv_kernel(const float* __restrict__ x,
                                                      const unsigned short* __restrict__ wbuf,
                                                      const unsigned* __restrict__ slots,
                                                      const float* __restrict__ scal,
                                                      float* __restrict__ out)
{
    __shared__ __align__(16) unsigned short xs[340 * 32];   // 21760 B
    __shared__ float sred[4];

    // bijective XCD swizzle: 3136 blocks = 8 XCDs x 392 contiguous (= 2 images each)
    int bid = (blockIdx.x & 7) * 392 + (blockIdx.x >> 3);
    int tw = bid % 7;
    int rest = bid / 7;
    int th = rest % 28;
    int n  = rest / 28;
    int h0 = th * TH, w0 = tw * TW;

    int tid = threadIdx.x;
    int lane = tid & 63, wv = tid >> 6;   // wv in 0..3

    const float* xn = x + n * (NCH * PLANE);

    // staging map: slot = tid&7 (4-px col group), c = tid>>3 (channel 0..31)
    int slot = tid & 7;
    int c = tid >> 3;
    const float* tb = xn + c * PLANE + w0 + slot * 4;
    int pixb = 1 + slot * 4;

    // ---- issue order: slots first (reduce waits only on these), then all x loads ----
    uint4 s0 = ((const uint4*)slots)[tid];
    uint4 s1 = ((const uint4*)slots)[tid + 256];
    float wscale = scal[0];

    float hv[3];
    #pragma unroll
    for (int it = 0; it < 3; ++it) {
        int e = tid + it * 256;
        hv[it] = 0.f;
        if (e < 640) {      // halo cols: 10 rows x 32 ch x 2 sides
            int side = e & 1, cc = (e >> 1) & 31, hp = e >> 6;
            int gh = h0 - 1 + hp;
            int gw = side ? (w0 + TW) : (w0 - 1);
            int ghc = gh < 0 ? 0 : (gh > HW - 1 ? HW - 1 : gh);
            int gwc = gw < 0 ? 0 : (gw > HW - 1 ? HW - 1 : gw);
            hv[it] = xn[cc * PLANE + ghc * HW + gwc];
        }
    }
    float4 va[5], vb[5];
    #pragma unroll
    for (int i = 0; i < 5; ++i) {
        int gh = h0 - 1 + i;
        int ghc = gh < 0 ? 0 : (gh > HW - 1 ? HW - 1 : gh);
        va[i] = *(const float4*)(tb + ghc * HW);
    }
    #pragma unroll
    for (int i = 0; i < 5; ++i) {
        int gh = h0 + 4 + i;              // rows 5..9: gh = h0-1+5+i
        int ghc = gh > HW - 1 ? HW - 1 : gh;
        vb[i] = *(const float4*)(tb + ghc * HW);
    }

    // ---- xmax reduce (x loads still in flight) ----
    float m2 = fmaxf(fmaxf(fmaxf(__uint_as_float(s0.x), __uint_as_float(s0.y)),
                           fmaxf(__uint_as_float(s0.z), __uint_as_float(s0.w))),
                     fmaxf(fmaxf(__uint_as_float(s1.x), __uint_as_float(s1.y)),
                           fmaxf(__uint_as_float(s1.z), __uint_as_float(s1.w))));
    #pragma unroll
    for (int off = 32; off > 0; off >>= 1)
        m2 = fmaxf(m2, __shfl_xor(m2, off));
    if (lane == 0) sred[wv] = m2;
    __syncthreads();
    float xmax = fmaxf(fmaxf(sred[0], sred[1]), fmaxf(sred[2], sred[3]));
    float xscale = xmax + 1e-5f;
    float inv = 127.f / xscale;
    float osc = (xscale / 127.f) * wscale;

    // ---- quantize + LDS writes: rows 0-4, halo, rows 5-9 (progressive drain) ----
    #pragma unroll
    for (int i = 0; i < 5; ++i) {
        int gh = h0 - 1 + i;
        float vs = ((unsigned)gh < (unsigned)HW) ? inv : 0.f;
        int p0 = i * 34 + pixb;
        xs[lds_h(p0 + 0, c)] = q8(va[i].x * vs);
        xs[lds_h(p0 + 1, c)] = q8(va[i].y * vs);
        xs[lds_h(p0 + 2, c)] = q8(va[i].z * vs);
        xs[lds_h(p0 + 3, c)] = q8(va[i].w * vs);
    }
    #pragma unroll
    for (int it = 0; it < 3; ++it) {
        int e = tid + it * 256;
        if (e < 640) {
            int side = e & 1, cc = (e >> 1) & 31, hp = e >> 6;
            int gh = h0 - 1 + hp;
            int gw = side ? (w0 + TW) : (w0 - 1);
            float vs = ((unsigned)gh < (unsigned)HW && (unsigned)gw < (unsigned)HW)
                           ? inv : 0.f;
            xs[lds_h(hp * 34 + (side ? 33 : 0), cc)] = q8(hv[it] * vs);
        }
    }
    #pragma unroll
    for (int i = 0; i < 5; ++i) {
        int gh = h0 + 4 + i;
        float vs = (gh < HW) ? inv : 0.f;
        int p0 = (5 + i) * 34 + pixb;
        xs[lds_h(p0 + 0, c)] = q8(vb[i].x * vs);
        xs[lds_h(p0 + 1, c)] = q8(vb[i].y * vs);
        xs[lds_h(p0 + 2, c)] = q8(vb[i].z * vs);
        xs[lds_h(p0 + 3, c)] = q8(vb[i].w * vs);
    }
    __syncthreads();

    // ---- MFMA: 9 taps x [2 row][2 pixblock][2 kblock], one-ahead weight prefetch ----
    // wave wv computes output rows h0 + 2*wv + {0,1}
    int ln = lane & 15, cb = lane >> 4;
    f32x4 acc[2][2][2] = {};
    const short8* wfp = (const short8*)wbuf;
    short8 wa = wfp[lane];
    short8 wb = wfp[64 + lane];
    for (int tap = 0; tap < 9; ++tap) {
        short8 na, nb;
        if (tap < 8) {
            na = wfp[(2 * tap + 2) * 64 + lane];
            nb = wfp[(2 * tap + 3) * 64 + lane];
        }
        int r = tap / 3;
        int s2 = tap - r * 3;
        #pragma unroll
        for (int ri = 0; ri < 2; ++ri) {
            #pragma unroll
            for (int pb = 0; pb < 2; ++pb) {
                int pix = (wv * 2 + ri + r) * 34 + pb * 16 + ln + s2;
                int sw = (pix & 3) ^ ((pix >> 2) & 3);
                const short8 a = *(const short8*)&xs[pix * 32 + (((cb ^ sw) & 3) << 3)];
                acc[ri][pb][0] = __builtin_amdgcn_mfma_f32_16x16x32_bf16(
                    a, wa, acc[ri][pb][0], 0, 0, 0);
                acc[ri][pb][1] = __builtin_amdgcn_mfma_f32_16x16x32_bf16(
                    a, wb, acc[ri][pb][1], 0, 0, 0);
            }
        }
        wa = na;
        wb = nb;
    }

    // ---- epilogue: D row = pixel -> lane holds 4 consecutive px: float4 stores ----
    float* on = out + n * (NCH * PLANE);
    #pragma unroll
    for (int ri = 0; ri < 2; ++ri) {
        int h = h0 + wv * 2 + ri;
        #pragma unroll
        for (int pb = 0; pb < 2; ++pb) {
            int wcol = w0 + pb * 16 + cb * 4;
            #pragma unroll
            for (int kb = 0; kb < 2; ++kb) {
                int k = kb * 16 + ln;
                f32x4 o;
                o[0] = acc[ri][pb][kb][0] * osc;
                o[1] = acc[ri][pb][kb][1] * osc;
                o[2] = acc[ri][pb][kb][2] * osc;
                o[3] = acc[ri][pb][kb][3] * osc;
                *(f32x4*)&on[(k * HW + h) * HW + wcol] = o;
            }
        }
    }
}

extern "C" void kernel_launch(void* const* d_in, const int* in_sizes, int n_in,
                              void* d_out, int out_size, void* d_ws, size_t ws_size,
                              hipStream_t stream)
{
    const float* x = (const float*)d_in[0];
    const float* w = (const float*)d_in[1];
    float* outp = (float*)d_out;
    unsigned* slots = (unsigned*)d_ws;
    float* scal = (float*)((char*)d_ws + 8192);
    unsigned short* wbuf = (unsigned short*)((char*)d_ws + 8448);

    absmax_kernel<<<2049, 256, 0, stream>>>(x, w, slots, scal, wbuf);
    conv_kernel<<<16 * 28 * 7, 256, 0, stream>>>(x, wbuf, slots, scal, outp);
}

// Round 12
// 72.980 us; speedup vs baseline: 1.1574x; 1.0069x over previous
//
#include <hip/hip_runtime.h>

// BitConv2d: x (16,32,224,224) f32, w (32,32,3,3) f32, out (16,32,224,224) f32.
// out = conv(x_q, w_q) * (x_scale/127 * w_scale); x_q in [-128,127], w_q in {-1,0,1}.
// Both exact in bf16 -> bf16 MFMA computes the integer conv exactly (|sum| < 2^24).
//
// 2 dispatches: absmax (2049 blocks: weight-quant block FIRST at idx 0 so it
// overlaps the x-pass instead of tailing it, + 2048 x-slices), conv (3136
// blocks x one 8x32 tile, 256 thr, 5 blocks/CU).

typedef __attribute__((ext_vector_type(8))) short short8;
typedef __attribute__((ext_vector_type(4))) float f32x4;

#define HW    224
#define NCH   32
#define PLANE (HW * HW)   // 50176
#define TH 8
#define TW 32
#define NX4   (16 * NCH * PLANE / 4)
// LDS tile: 340 pixels (10 rows x 34 cols) x 32 ch bf16 = 21760 B, granule-XOR swizzled.

__device__ __forceinline__ int lds_h(int pix, int c) {
    int sw = (pix & 3) ^ ((pix >> 2) & 3);
    return pix * 32 + (c & 7) + ((((c >> 3) ^ sw) & 3) << 3);
}

__device__ __forceinline__ unsigned short q8(float v) {
    float q = rintf(fminf(127.f, fmaxf(-128.f, v)));   // round-half-even like jnp.round
    return (unsigned short)(__float_as_uint(q) >> 16); // exact bf16 of small ints
}

// ws layout: [0, 8192) = u32 slots[2048] (fully rewritten each call);
// 8192: scal[0] = wscale; 8448: wbuf 18 frags x 512 bf16.
// frag (tap*2+kb): lane l elem j = w_q[kout = kb*16+(l&15)][c = (l>>4)*8+j][tap/3][tap%3]

__global__ __launch_bounds__(256) void absmax_kernel(const float* __restrict__ x,
                                                     const float* __restrict__ w,
                                                     unsigned* __restrict__ slots,
                                                     float* __restrict__ scal,
                                                     unsigned short* __restrict__ wbuf)
{
    int tid = threadIdx.x;
    int lane = tid & 63, wv = tid >> 6;

    if (blockIdx.x == 0) {
        // ---- weight block (FIRST: overlaps the x-pass, no serial tail) ----
        float s = 0.f;
        for (int i = tid; i < 9216; i += 256) s += fabsf(w[i]);
        #pragma unroll
        for (int off = 32; off > 0; off >>= 1) s += __shfl_xor(s, off);
        __shared__ float sm[4];
        __shared__ float s_ws;
        if (lane == 0) sm[wv] = s;
        __syncthreads();
        if (tid == 0) {
            float wscale = (sm[0] + sm[1] + sm[2] + sm[3]) / 9216.f + 1e-5f;
            scal[0] = wscale;
            s_ws = wscale;
        }
        __syncthreads();
        float wscale = s_ws;
        for (int o = tid; o < 9216; o += 256) {
            int frag = o >> 9, rem = o & 511;
            int l = rem >> 3, j = rem & 7;
            int tap = frag >> 1, kb = frag & 1;
            int kout = kb * 16 + (l & 15);
            int c = ((l >> 4) << 3) + j;
            int r = tap / 3, ss = tap % 3;
            float wv2 = w[((kout * 32 + c) * 3 + r) * 3 + ss];
            float q = fminf(1.f, fmaxf(-1.f, rintf(wv2 / wscale)));
            wbuf[o] = (unsigned short)(__float_as_uint(q) >> 16);   // exact bf16
        }
        return;
    }

    // ---- x-slice absmax (slice index = blockIdx - 1) ----
    const float4* x4 = (const float4*)x;
    float m = 0.f;
    for (int i = (blockIdx.x - 1) * 256 + tid; i < NX4; i += 2048 * 256) {
        float4 v = x4[i];
        m = fmaxf(m, fmaxf(fmaxf(fabsf(v.x), fabsf(v.y)),
                           fmaxf(fabsf(v.z), fabsf(v.w))));
    }
    #pragma unroll
    for (int off = 32; off > 0; off >>= 1)
        m = fmaxf(m, __shfl_xor(m, off));
    __shared__ float wm[4];
    if (lane == 0) wm[wv] = m;
    __syncthreads();
    if (tid == 0) {
        m = fmaxf(fmaxf(wm[0], wm[1]), fmaxf(wm[2], wm[3]));
        slots[blockIdx.x - 1] = __float_as_uint(m);   // plain store, no atomics
    }
}

__global__ __launch_bounds__(256, 5) void conv_kernel(const float* __restrict__ x,
                                                      const unsigned short* __restrict__ wbuf,
                                                      const unsigned* __restrict__ slots,
                                                      const float* __restrict__ scal,
                                                      float* __restrict__ out)
{
    __shared__ __align__(16) unsigned short xs[340 * 32];   // 21760 B
    __shared__ float sred[4];

    // bijective XCD swizzle: 3136 blocks = 8 XCDs x 392 contiguous (= 2 images each)
    int bid = (blockIdx.x & 7) * 392 + (blockIdx.x >> 3);
    int tw = bid % 7;
    int rest = bid / 7;
    int th = rest % 28;
    int n  = rest / 28;
    int h0 = th * TH, w0 = tw * TW;

    int tid = threadIdx.x;
    int lane = tid & 63, wv = tid >> 6;   // wv in 0..3

    const float* xn = x + n * (NCH * PLANE);

    // staging map: slot = tid&7 (4-px col group), c = tid>>3 (channel 0..31)
    int slot = tid & 7;
    int c = tid >> 3;
    const float* tb = xn + c * PLANE + w0 + slot * 4;
    int pixb = 1 + slot * 4;

    // ---- issue order: slots first (reduce waits only on these), then all x loads ----
    uint4 s0 = ((const uint4*)slots)[tid];
    uint4 s1 = ((const uint4*)slots)[tid + 256];
    float wscale = scal[0];

    float hv[3];
    #pragma unroll
    for (int it = 0; it < 3; ++it) {
        int e = tid + it * 256;
        hv[it] = 0.f;
        if (e < 640) {      // halo cols: 10 rows x 32 ch x 2 sides
            int side = e & 1, cc = (e >> 1) & 31, hp = e >> 6;
            int gh = h0 - 1 + hp;
            int gw = side ? (w0 + TW) : (w0 - 1);
            int ghc = gh < 0 ? 0 : (gh > HW - 1 ? HW - 1 : gh);
            int gwc = gw < 0 ? 0 : (gw > HW - 1 ? HW - 1 : gw);
            hv[it] = xn[cc * PLANE + ghc * HW + gwc];
        }
    }
    float4 va[5], vb[5];
    #pragma unroll
    for (int i = 0; i < 5; ++i) {
        int gh = h0 - 1 + i;
        int ghc = gh < 0 ? 0 : (gh > HW - 1 ? HW - 1 : gh);
        va[i] = *(const float4*)(tb + ghc * HW);
    }
    #pragma unroll
    for (int i = 0; i < 5; ++i) {
        int gh = h0 + 4 + i;              // rows 5..9: gh = h0-1+5+i
        int ghc = gh > HW - 1 ? HW - 1 : gh;
        vb[i] = *(const float4*)(tb + ghc * HW);
    }

    // ---- xmax reduce (x loads still in flight) ----
    float m2 = fmaxf(fmaxf(fmaxf(__uint_as_float(s0.x), __uint_as_float(s0.y)),
                           fmaxf(__uint_as_float(s0.z), __uint_as_float(s0.w))),
                     fmaxf(fmaxf(__uint_as_float(s1.x), __uint_as_float(s1.y)),
                           fmaxf(__uint_as_float(s1.z), __uint_as_float(s1.w))));
    #pragma unroll
    for (int off = 32; off > 0; off >>= 1)
        m2 = fmaxf(m2, __shfl_xor(m2, off));
    if (lane == 0) sred[wv] = m2;
    __syncthreads();
    float xmax = fmaxf(fmaxf(sred[0], sred[1]), fmaxf(sred[2], sred[3]));
    float xscale = xmax + 1e-5f;
    float inv = 127.f / xscale;
    float osc = (xscale / 127.f) * wscale;

    // ---- quantize + LDS writes: rows 0-4, halo, rows 5-9 (progressive drain) ----
    #pragma unroll
    for (int i = 0; i < 5; ++i) {
        int gh = h0 - 1 + i;
        float vs = ((unsigned)gh < (unsigned)HW) ? inv : 0.f;
        int p0 = i * 34 + pixb;
        xs[lds_h(p0 + 0, c)] = q8(va[i].x * vs);
        xs[lds_h(p0 + 1, c)] = q8(va[i].y * vs);
        xs[lds_h(p0 + 2, c)] = q8(va[i].z * vs);
        xs[lds_h(p0 + 3, c)] = q8(va[i].w * vs);
    }
    #pragma unroll
    for (int it = 0; it < 3; ++it) {
        int e = tid + it * 256;
        if (e < 640) {
            int side = e & 1, cc = (e >> 1) & 31, hp = e >> 6;
            int gh = h0 - 1 + hp;
            int gw = side ? (w0 + TW) : (w0 - 1);
            float vs = ((unsigned)gh < (unsigned)HW && (unsigned)gw < (unsigned)HW)
                           ? inv : 0.f;
            xs[lds_h(hp * 34 + (side ? 33 : 0), cc)] = q8(hv[it] * vs);
        }
    }
    #pragma unroll
    for (int i = 0; i < 5; ++i) {
        int gh = h0 + 4 + i;
        float vs = (gh < HW) ? inv : 0.f;
        int p0 = (5 + i) * 34 + pixb;
        xs[lds_h(p0 + 0, c)] = q8(vb[i].x * vs);
        xs[lds_h(p0 + 1, c)] = q8(vb[i].y * vs);
        xs[lds_h(p0 + 2, c)] = q8(vb[i].z * vs);
        xs[lds_h(p0 + 3, c)] = q8(vb[i].w * vs);
    }
    __syncthreads();

    // ---- MFMA: 9 taps x [2 row][2 pixblock][2 kblock], one-ahead weight prefetch ----
    // wave wv computes output rows h0 + 2*wv + {0,1}
    int ln = lane & 15, cb = lane >> 4;
    f32x4 acc[2][2][2] = {};
    const short8* wfp = (const short8*)wbuf;
    short8 wa = wfp[lane];
    short8 wb = wfp[64 + lane];
    for (int tap = 0; tap < 9; ++tap) {
        short8 na, nb;
        if (tap < 8) {
            na = wfp[(2 * tap + 2) * 64 + lane];
            nb = wfp[(2 * tap + 3) * 64 + lane];
        }
        int r = tap / 3;
        int s2 = tap - r * 3;
        #pragma unroll
        for (int ri = 0; ri < 2; ++ri) {
            #pragma unroll
            for (int pb = 0; pb < 2; ++pb) {
                int pix = (wv * 2 + ri + r) * 34 + pb * 16 + ln + s2;
                int sw = (pix & 3) ^ ((pix >> 2) & 3);
                const short8 a = *(const short8*)&xs[pix * 32 + (((cb ^ sw) & 3) << 3)];
                acc[ri][pb][0] = __builtin_amdgcn_mfma_f32_16x16x32_bf16(
                    a, wa, acc[ri][pb][0], 0, 0, 0);
                acc[ri][pb][1] = __builtin_amdgcn_mfma_f32_16x16x32_bf16(
                    a, wb, acc[ri][pb][1], 0, 0, 0);
            }
        }
        wa = na;
        wb = nb;
    }

    // ---- epilogue: D row = pixel -> lane holds 4 consecutive px: float4 stores ----
    float* on = out + n * (NCH * PLANE);
    #pragma unroll
    for (int ri = 0; ri < 2; ++ri) {
        int h = h0 + wv * 2 + ri;
        #pragma unroll
        for (int pb = 0; pb < 2; ++pb) {
            int wcol = w0 + pb * 16 + cb * 4;
            #pragma unroll
            for (int kb = 0; kb < 2; ++kb) {
                int k = kb * 16 + ln;
                f32x4 o;
                o[0] = acc[ri][pb][kb][0] * osc;
                o[1] = acc[ri][pb][kb][1] * osc;
                o[2] = acc[ri][pb][kb][2] * osc;
                o[3] = acc[ri][pb][kb][3] * osc;
                *(f32x4*)&on[(k * HW + h) * HW + wcol] = o;
            }
        }
    }
}

extern "C" void kernel_launch(void* const* d_in, const int* in_sizes, int n_in,
                              void* d_out, int out_size, void* d_ws, size_t ws_size,
                              hipStream_t stream)
{
    const float* x = (const float*)d_in[0];
    const float* w = (const float*)d_in[1];
    float* outp = (float*)d_out;
    unsigned* slots = (unsigned*)d_ws;
    float* scal = (float*)((char*)d_ws + 8192);
    unsigned short* wbuf = (unsigned short*)((char*)d_ws + 8448);

    absmax_kernel<<<2049, 256, 0, stream>>>(x, w, slots, scal, wbuf);
    conv_kernel<<<16 * 28 * 7, 256, 0, stream>>>(x, wbuf, slots, scal, outp);
}